// Round 22
// baseline (927.834 us; speedup 1.0000x reference)
//
#include <hip/hip_runtime.h>
#include <stdint.h>

#define B_   4
#define T_   4096
#define D_   1024
#define H_   16
#define M_   16384
#define NTOT 1536
#define BM   128
#define BN   64
#define BKK  16
#define NIT  (D_ / BKK)    // 64
#define KC   384           // OpenBLAS SGEMM_DEFAULT_Q

typedef unsigned short u16;
typedef unsigned long long u64;

__device__ __forceinline__ float bf16r(float f) {
    unsigned int u = __float_as_uint(f);
    u += 0x7FFFu + ((u >> 16) & 1u);
    return __uint_as_float(u & 0xFFFF0000u);
}

// ---------------------------------------------------------------------------
// GEMM on RAW f32 inputs, OpenBLAS order (serial FMA per element within
// KC=384 panels, C += per panel, (P0+P1)+P2). 128x64 block, 8x4/thread.
// LDS ping-pong double-buffer + register prefetch: one barrier per K-iter,
// global L2 latency hidden under the 16-k FMA block. Accumulation order
// bit-identical to the proven R19/R21 kernels.
// ---------------------------------------------------------------------------
__global__ __launch_bounds__(256) void gemm_pack_kernel(
    const float* __restrict__ x, const float* __restrict__ Wq,
    const float* __restrict__ Wk, const float* __restrict__ Wv,
    u16* __restrict__ qc, u16* __restrict__ kc, u64* __restrict__ vc)
{
    __shared__ float As[2][BKK][BM + 4];   // 2 x [16][132]
    __shared__ float Bs[2][BKK][BN + 4];   // 2 x [16][68]
    __shared__ unsigned char sb[BM][17];

    const int tid = threadIdx.x;
    const int tx = tid & 15;            // N: cols tx*4..+3
    const int ty = tid >> 4;            // M: rows ty*4+i and 64+ty*4+i
    const int n0 = blockIdx.x * BN;     // x-major: n-tiles share x rows in L2
    const int m0 = blockIdx.y * BM;

    const float* Wsrc; int f0;
    if (n0 < 256)      { Wsrc = Wq; f0 = n0; }
    else if (n0 < 512) { Wsrc = Wk; f0 = n0 - 256; }
    else               { Wsrc = Wv; f0 = n0 - 512; }

    // staging indices (constant per thread)
    const int xm0 = tid >> 2;                 // 0..63   (l=0)
    const int xm1 = (tid + 256) >> 2;         // 64..127 (l=1)
    const int xkg = tid & 3;                  // float4 group in k
    const int wn  = tid >> 2;                 // 0..63
    const int wkg = tid & 3;
    const float* xbase0 = x + (size_t)(m0 + xm0) * D_ + xkg * 4;
    const float* xbase1 = x + (size_t)(m0 + xm1) * D_ + xkg * 4;
    const float* wbase  = Wsrc + (size_t)(f0 + wn) * D_ + wkg * 4;

    float run[8][4], tot[8][4];
    #pragma unroll
    for (int i = 0; i < 8; ++i)
        #pragma unroll
        for (int j = 0; j < 4; ++j) { run[i][j] = 0.f; tot[i][j] = 0.f; }

    // stage tile 0 into buffer 0
    {
        float4 v0 = *(const float4*)(xbase0);
        float4 v1 = *(const float4*)(xbase1);
        float4 w0 = *(const float4*)(wbase);
        As[0][xkg * 4 + 0][xm0] = v0.x; As[0][xkg * 4 + 1][xm0] = v0.y;
        As[0][xkg * 4 + 2][xm0] = v0.z; As[0][xkg * 4 + 3][xm0] = v0.w;
        As[0][xkg * 4 + 0][xm1] = v1.x; As[0][xkg * 4 + 1][xm1] = v1.y;
        As[0][xkg * 4 + 2][xm1] = v1.z; As[0][xkg * 4 + 3][xm1] = v1.w;
        Bs[0][wkg * 4 + 0][wn] = w0.x;  Bs[0][wkg * 4 + 1][wn] = w0.y;
        Bs[0][wkg * 4 + 2][wn] = w0.z;  Bs[0][wkg * 4 + 3][wn] = w0.w;
    }
    __syncthreads();

    int cur = 0;
    for (int it = 0; it < NIT; ++it) {
        // prefetch next K-tile into registers (issued before compute)
        float4 px0, px1, pw0;
        const bool more = (it + 1 < NIT);
        if (more) {
            const int koff = (it + 1) * BKK;
            px0 = *(const float4*)(xbase0 + koff);
            px1 = *(const float4*)(xbase1 + koff);
            pw0 = *(const float4*)(wbase + koff);
        }

        // compute current buffer
        #pragma unroll
        for (int k = 0; k < BKK; ++k) {
            float4 a0 = *(const float4*)&As[cur][k][ty * 4];
            float4 a1 = *(const float4*)&As[cur][k][64 + ty * 4];
            float4 b0 = *(const float4*)&Bs[cur][k][tx * 4];
#define FMAROW(I, AV)                                              \
            run[I][0] = __builtin_fmaf(AV, b0.x, run[I][0]);       \
            run[I][1] = __builtin_fmaf(AV, b0.y, run[I][1]);       \
            run[I][2] = __builtin_fmaf(AV, b0.z, run[I][2]);       \
            run[I][3] = __builtin_fmaf(AV, b0.w, run[I][3]);
            FMAROW(0, a0.x) FMAROW(1, a0.y) FMAROW(2, a0.z) FMAROW(3, a0.w)
            FMAROW(4, a1.x) FMAROW(5, a1.y) FMAROW(6, a1.z) FMAROW(7, a1.w)
#undef FMAROW
        }

        // OpenBLAS panel boundary after k = 384 (it=23) and k = 768 (it=47)
        if (it == 23 || it == 47) {
            #pragma unroll
            for (int i = 0; i < 8; ++i)
                #pragma unroll
                for (int j = 0; j < 4; ++j) {
                    tot[i][j] = tot[i][j] + run[i][j];
                    run[i][j] = 0.f;
                }
        }

        // write prefetched tile to the other buffer (no reader conflict)
        if (more) {
            const int nb = cur ^ 1;
            As[nb][xkg * 4 + 0][xm0] = px0.x; As[nb][xkg * 4 + 1][xm0] = px0.y;
            As[nb][xkg * 4 + 2][xm0] = px0.z; As[nb][xkg * 4 + 3][xm0] = px0.w;
            As[nb][xkg * 4 + 0][xm1] = px1.x; As[nb][xkg * 4 + 1][xm1] = px1.y;
            As[nb][xkg * 4 + 2][xm1] = px1.z; As[nb][xkg * 4 + 3][xm1] = px1.w;
            Bs[nb][wkg * 4 + 0][wn] = pw0.x;  Bs[nb][wkg * 4 + 1][wn] = pw0.y;
            Bs[nb][wkg * 4 + 2][wn] = pw0.z;  Bs[nb][wkg * 4 + 3][wn] = pw0.w;
        }
        __syncthreads();
        cur ^= 1;
    }

    // sign-pack: thread -> 8 nibbles (one per row, cols tx*4..+3)
    #pragma unroll
    for (int i = 0; i < 8; ++i) {
        const int r = (i < 4) ? (ty * 4 + i) : (64 + ty * 4 + (i - 4));
        unsigned char nb = 0;
        #pragma unroll
        for (int j = 0; j < 4; ++j) {
            float v = tot[i][j] + run[i][j];   // C = (P0+P1)+P2
            nb |= (unsigned char)((v > 0.0f) ? (1u << j) : 0u);
        }
        sb[r][tx] = nb;
    }
    __syncthreads();

    if (tid < BM) {
        const int r = tid;
        u64 row = 0ULL;
        #pragma unroll
        for (int nb2 = 0; nb2 < 16; ++nb2)
            row |= (u64)(sb[r][nb2] & 0xFu) << (nb2 * 4);
        const int m = m0 + r;
        const int b = m >> 12;
        const int t = m & (T_ - 1);
        if (n0 < 512) {
            u16* dst = (n0 < 256) ? qc : kc;
            const int hb = (n0 & 255) >> 4;
            #pragma unroll
            for (int g = 0; g < 4; ++g)
                dst[((size_t)(b * H_ + hb + g)) * T_ + t] = (u16)((row >> (g * 16)) & 0xFFFFULL);
        } else {
            const int h = (n0 - 512) >> 6;
            vc[((size_t)(b * H_ + h)) * T_ + t] = row;
        }
    }
}

// ---------------------------------------------------------------------------
// Fused resolve + expand (bit-identical to the R19 proven kernel).
// ---------------------------------------------------------------------------
__global__ __launch_bounds__(256) void resolve_expand_kernel(
    const u16* __restrict__ qc, const u16* __restrict__ kc,
    const u64* __restrict__ vc,
    const float* __restrict__ emb0, const float* __restrict__ emb1,
    float* __restrict__ out)
{
    __shared__ u16 keys[T_];
    __shared__ u16 pos[T_];
    __shared__ unsigned int cnt[256];
    __shared__ unsigned int offs[257];
    __shared__ float e_lo[64], e_hi[64];

    const int bh = blockIdx.x;
    const int b = bh >> 4, h = bh & 15;
    const u16* kck = kc + (size_t)bh * T_;
    const u16* qck = qc + (size_t)bh * T_;
    const u64* vck = vc + (size_t)bh * T_;
    const int tid = threadIdx.x;

    if (tid < 64) {
        e_lo[tid] = bf16r(emb0[h * 64 + tid]);
        e_hi[tid] = bf16r(emb1[h * 64 + tid]);
    }
    cnt[tid] = 0;
    __syncthreads();
    for (int t = tid; t < T_; t += 256) {
        u16 kv = kck[t];
        keys[t] = kv;
        atomicAdd(&cnt[kv & 255], 1u);
    }
    __syncthreads();
    if (tid == 0) {
        unsigned int s = 0;
        for (int i = 0; i < 256; ++i) { offs[i] = s; s += cnt[i]; }
        offs[256] = s;
    }
    __syncthreads();
    cnt[tid] = offs[tid];
    __syncthreads();
    for (int t = tid; t < T_; t += 256) {
        unsigned int p = atomicAdd(&cnt[keys[t] & 255], 1u);
        pos[p] = (u16)t;
    }
    __syncthreads();
    for (int t = tid; t < T_; t += 256) {
        u16 code = qck[t];
        const int bkt = code & 255;
        int best = -1;
        const unsigned int s = offs[bkt], e = offs[bkt + 1];
        for (unsigned int it = s; it < e; ++it) {
            int j = (int)pos[it];
            if (j < t && keys[j] == code && j > best) best = j;
        }
        u64 yv = (best >= 0) ? vck[best] : 0ULL;
        float* orow = out + ((size_t)(b * T_ + t)) * D_ + h * 64;
        #pragma unroll
        for (int e2 = 0; e2 < 64; ++e2)
            orow[e2] = ((yv >> e2) & 1ULL) ? e_hi[e2] : e_lo[e2];
    }
}

// ---------------------------------------------------------------------------
extern "C" void kernel_launch(void* const* d_in, const int* in_sizes, int n_in,
                              void* d_out, int out_size, void* d_ws, size_t ws_size,
                              hipStream_t stream)
{
    const float* x  = (const float*)d_in[0];
    const float* Wq = (const float*)d_in[1];
    const float* Wk = (const float*)d_in[2];
    const float* Wv = (const float*)d_in[3];
    const float* e0 = (const float*)d_in[4];
    const float* e1 = (const float*)d_in[5];

    char* ws = (char*)d_ws;
    // footprint 3 MB (safe): qc 512K | kc 512K | vc 2M
    u16* qc = (u16*)(ws + 0);
    u16* kc = (u16*)(ws + 524288);
    u64* vc = (u64*)(ws + 1048576);
    float* out = (float*)d_out;

    dim3 gA(NTOT / BN, M_ / BM);   // (24, 128), x-major shares x-rows in L2
    gemm_pack_kernel<<<gA, 256, 0, stream>>>(x, Wq, Wk, Wv, qc, kc, vc);
    resolve_expand_kernel<<<B_ * H_, 256, 0, stream>>>(qc, kc, vc, e0, e1, out);
}

// Round 23
// 923.222 us; speedup vs baseline: 1.0050x; 1.0050x over previous
//
#include <hip/hip_runtime.h>
#include <stdint.h>

#define B_   4
#define T_   4096
#define D_   1024
#define H_   16
#define M_   16384
#define NTOT 1536
#define BM   128
#define BN   64
#define BKK  16
#define NIT  (D_ / BKK)    // 64
#define KC   384           // OpenBLAS SGEMM_DEFAULT_Q

typedef unsigned short u16;
typedef unsigned long long u64;

__device__ __forceinline__ float bf16r(float f) {
    unsigned int u = __float_as_uint(f);
    u += 0x7FFFu + ((u >> 16) & 1u);
    return __uint_as_float(u & 0xFFFF0000u);
}

// ---------------------------------------------------------------------------
// GEMM on RAW f32 inputs, OpenBLAS order (serial FMA per element within
// KC=384 panels, C += per panel, (P0+P1)+P2). 128x64 block, 8x4/thread.
// SINGLE LDS buffer + load-early software pipeline: loads for tile it+1 are
// issued right after tile it's LDS writes, so the vmcnt wait happens one
// full compute phase (~1024 VALU cyc) later. Only +12 VGPR vs R21.
// Per-element accumulation order bit-identical to the proven R19/R21 kernels.
// ---------------------------------------------------------------------------
__global__ __launch_bounds__(256) void gemm_pack_kernel(
    const float* __restrict__ x, const float* __restrict__ Wq,
    const float* __restrict__ Wk, const float* __restrict__ Wv,
    u16* __restrict__ qc, u16* __restrict__ kc, u64* __restrict__ vc)
{
    __shared__ float As[BKK][BM + 4];   // [16][132]
    __shared__ float Bs[BKK][BN + 4];   // [16][68]
    __shared__ unsigned char sb[BM][17];

    const int tid = threadIdx.x;
    const int tx = tid & 15;            // N: cols tx*4..+3
    const int ty = tid >> 4;            // M: rows ty*4+i and 64+ty*4+i
    const int n0 = blockIdx.x * BN;     // x-major: n-tiles share x rows in L2
    const int m0 = blockIdx.y * BM;

    const float* Wsrc; int f0;
    if (n0 < 256)      { Wsrc = Wq; f0 = n0; }
    else if (n0 < 512) { Wsrc = Wk; f0 = n0 - 256; }
    else               { Wsrc = Wv; f0 = n0 - 512; }

    // staging indices (constant per thread)
    const int xm0 = tid >> 2;                 // 0..63
    const int xm1 = xm0 + 64;                 // 64..127
    const int xkg = tid & 3;                  // float4 group in k
    const float* xbase0 = x + (size_t)(m0 + xm0) * D_ + xkg * 4;
    const float* xbase1 = x + (size_t)(m0 + xm1) * D_ + xkg * 4;
    const float* wbase  = Wsrc + (size_t)(f0 + xm0) * D_ + xkg * 4;

    float run[8][4], tot[8][4];
    #pragma unroll
    for (int i = 0; i < 8; ++i)
        #pragma unroll
        for (int j = 0; j < 4; ++j) { run[i][j] = 0.f; tot[i][j] = 0.f; }

    // prologue: load tile 0 into staging registers
    float4 px0 = *(const float4*)(xbase0);
    float4 px1 = *(const float4*)(xbase1);
    float4 pw0 = *(const float4*)(wbase);

    for (int it = 0; it < NIT; ++it) {
        __syncthreads();   // previous compute done -> LDS safe to overwrite

        // write staged tile (loaded one iteration ago -> vmcnt long satisfied)
        As[xkg * 4 + 0][xm0] = px0.x; As[xkg * 4 + 1][xm0] = px0.y;
        As[xkg * 4 + 2][xm0] = px0.z; As[xkg * 4 + 3][xm0] = px0.w;
        As[xkg * 4 + 0][xm1] = px1.x; As[xkg * 4 + 1][xm1] = px1.y;
        As[xkg * 4 + 2][xm1] = px1.z; As[xkg * 4 + 3][xm1] = px1.w;
        Bs[xkg * 4 + 0][xm0] = pw0.x; Bs[xkg * 4 + 1][xm0] = pw0.y;
        Bs[xkg * 4 + 2][xm0] = pw0.z; Bs[xkg * 4 + 3][xm0] = pw0.w;

        // issue next tile's loads now -- they fly during the compute below
        if (it + 1 < NIT) {
            const int koff = (it + 1) * BKK;
            px0 = *(const float4*)(xbase0 + koff);
            px1 = *(const float4*)(xbase1 + koff);
            pw0 = *(const float4*)(wbase + koff);
        }

        __syncthreads();   // LDS tile ready

        #pragma unroll
        for (int k = 0; k < BKK; ++k) {
            float4 a0 = *(const float4*)&As[k][ty * 4];
            float4 a1 = *(const float4*)&As[k][64 + ty * 4];
            float4 b0 = *(const float4*)&Bs[k][tx * 4];
#define FMAROW(I, AV)                                              \
            run[I][0] = __builtin_fmaf(AV, b0.x, run[I][0]);       \
            run[I][1] = __builtin_fmaf(AV, b0.y, run[I][1]);       \
            run[I][2] = __builtin_fmaf(AV, b0.z, run[I][2]);       \
            run[I][3] = __builtin_fmaf(AV, b0.w, run[I][3]);
            FMAROW(0, a0.x) FMAROW(1, a0.y) FMAROW(2, a0.z) FMAROW(3, a0.w)
            FMAROW(4, a1.x) FMAROW(5, a1.y) FMAROW(6, a1.z) FMAROW(7, a1.w)
#undef FMAROW
        }

        // OpenBLAS panel boundary after k=384 (it=23) and k=768 (it=47)
        if (it == 23 || it == 47) {
            #pragma unroll
            for (int i = 0; i < 8; ++i)
                #pragma unroll
                for (int j = 0; j < 4; ++j) {
                    tot[i][j] = tot[i][j] + run[i][j];
                    run[i][j] = 0.f;
                }
        }
    }
    __syncthreads();

    // sign-pack: thread -> 8 nibbles (one per row, cols tx*4..+3)
    #pragma unroll
    for (int i = 0; i < 8; ++i) {
        const int r = (i < 4) ? (ty * 4 + i) : (64 + ty * 4 + (i - 4));
        unsigned char nb = 0;
        #pragma unroll
        for (int j = 0; j < 4; ++j) {
            float v = tot[i][j] + run[i][j];   // C = (P0+P1)+P2
            nb |= (unsigned char)((v > 0.0f) ? (1u << j) : 0u);
        }
        sb[r][tx] = nb;
    }
    __syncthreads();

    if (tid < BM) {
        const int r = tid;
        u64 row = 0ULL;
        #pragma unroll
        for (int nb2 = 0; nb2 < 16; ++nb2)
            row |= (u64)(sb[r][nb2] & 0xFu) << (nb2 * 4);
        const int m = m0 + r;
        const int b = m >> 12;
        const int t = m & (T_ - 1);
        if (n0 < 512) {
            u16* dst = (n0 < 256) ? qc : kc;
            const int hb = (n0 & 255) >> 4;
            #pragma unroll
            for (int g = 0; g < 4; ++g)
                dst[((size_t)(b * H_ + hb + g)) * T_ + t] = (u16)((row >> (g * 16)) & 0xFFFFULL);
        } else {
            const int h = (n0 - 512) >> 6;
            vc[((size_t)(b * H_ + h)) * T_ + t] = row;
        }
    }
}

// ---------------------------------------------------------------------------
// Fused resolve + expand (bit-identical to the R19 proven kernel).
// ---------------------------------------------------------------------------
__global__ __launch_bounds__(256) void resolve_expand_kernel(
    const u16* __restrict__ qc, const u16* __restrict__ kc,
    const u64* __restrict__ vc,
    const float* __restrict__ emb0, const float* __restrict__ emb1,
    float* __restrict__ out)
{
    __shared__ u16 keys[T_];
    __shared__ u16 pos[T_];
    __shared__ unsigned int cnt[256];
    __shared__ unsigned int offs[257];
    __shared__ float e_lo[64], e_hi[64];

    const int bh = blockIdx.x;
    const int b = bh >> 4, h = bh & 15;
    const u16* kck = kc + (size_t)bh * T_;
    const u16* qck = qc + (size_t)bh * T_;
    const u64* vck = vc + (size_t)bh * T_;
    const int tid = threadIdx.x;

    if (tid < 64) {
        e_lo[tid] = bf16r(emb0[h * 64 + tid]);
        e_hi[tid] = bf16r(emb1[h * 64 + tid]);
    }
    cnt[tid] = 0;
    __syncthreads();
    for (int t = tid; t < T_; t += 256) {
        u16 kv = kck[t];
        keys[t] = kv;
        atomicAdd(&cnt[kv & 255], 1u);
    }
    __syncthreads();
    if (tid == 0) {
        unsigned int s = 0;
        for (int i = 0; i < 256; ++i) { offs[i] = s; s += cnt[i]; }
        offs[256] = s;
    }
    __syncthreads();
    cnt[tid] = offs[tid];
    __syncthreads();
    for (int t = tid; t < T_; t += 256) {
        unsigned int p = atomicAdd(&cnt[keys[t] & 255], 1u);
        pos[p] = (u16)t;
    }
    __syncthreads();
    for (int t = tid; t < T_; t += 256) {
        u16 code = qck[t];
        const int bkt = code & 255;
        int best = -1;
        const unsigned int s = offs[bkt], e = offs[bkt + 1];
        for (unsigned int it = s; it < e; ++it) {
            int j = (int)pos[it];
            if (j < t && keys[j] == code && j > best) best = j;
        }
        u64 yv = (best >= 0) ? vck[best] : 0ULL;
        float* orow = out + ((size_t)(b * T_ + t)) * D_ + h * 64;
        #pragma unroll
        for (int e2 = 0; e2 < 64; ++e2)
            orow[e2] = ((yv >> e2) & 1ULL) ? e_hi[e2] : e_lo[e2];
    }
}

// ---------------------------------------------------------------------------
extern "C" void kernel_launch(void* const* d_in, const int* in_sizes, int n_in,
                              void* d_out, int out_size, void* d_ws, size_t ws_size,
                              hipStream_t stream)
{
    const float* x  = (const float*)d_in[0];
    const float* Wq = (const float*)d_in[1];
    const float* Wk = (const float*)d_in[2];
    const float* Wv = (const float*)d_in[3];
    const float* e0 = (const float*)d_in[4];
    const float* e1 = (const float*)d_in[5];

    char* ws = (char*)d_ws;
    // footprint 3 MB (safe): qc 512K | kc 512K | vc 2M
    u16* qc = (u16*)(ws + 0);
    u16* kc = (u16*)(ws + 524288);
    u64* vc = (u64*)(ws + 1048576);
    float* out = (float*)d_out;

    dim3 gA(NTOT / BN, M_ / BM);   // (24, 128), x-major shares x-rows in L2
    gemm_pack_kernel<<<gA, 256, 0, stream>>>(x, Wq, Wk, Wv, qc, kc, vc);
    resolve_expand_kernel<<<B_ * H_, 256, 0, stream>>>(qc, kc, vc, e0, e1, out);
}